// Round 11
// baseline (655.449 us; speedup 1.0000x reference)
//
#include <hip/hip_runtime.h>
#include <math.h>

#define NPG 500      // nodes per graph
#define DIM 256      // feature dim
#define HID 64       // hidden dim
#define RATIO_NORM 600.0f

#define BM 256       // nodes per block
#define BK 16        // k per tile
#define XPAD 20      // x_lds row stride in floats (pad 16 -> 20: lm-groups cover all banks)
#define WPAD 68      // w_lds row stride in floats (pad 64 -> 68: 2-way max)

// ---------------------------------------------------------------- K1: scores
// score[n] = relu(x[n,:] @ Ws1 + bs1) @ Ws2 + bs2
// Tiled fp32 GEMM: 256x64 block tile, BK=16, dbuf LDS for x and W.
// 4 waves; per-thread 8 nodes x 8 h (64 FMA per 16 LDS floats -> LDS pipe
// no longer the broadcast wall). lane=(lm,ln): lm=lane&7 -> node m0=wv*64+lm,
// nodes m0+8i; ln=lane>>3 -> h n0=8*ln.
__global__ __launch_bounds__(256, 3) void k_score(
    const float* __restrict__ x,
    const float* __restrict__ Ws1,   // [DIM][HID] row-major
    const float* __restrict__ bs1,   // [HID]
    const float* __restrict__ Ws2,   // [HID]
    const float* __restrict__ bs2,   // [1]
    float* __restrict__ score, int N)
{
    __shared__ float xs[2][BM * XPAD];   // 2 x 20KB
    __shared__ float ws[2][BK * WPAD];   // 2 x 4.25KB

    int t = threadIdx.x;
    int nbase = blockIdx.x * BM;

    // staging roles
    int srow = t >> 2;           // x: node sub-row 0..63 (4 passes of 64)
    int schk = t & 3;            // x: 16B chunk 0..3 within BK
    int wrow = t >> 4;           // W: k row 0..15
    int wchk = t & 15;           // W: 16B chunk 0..15 within 64 h

    // compute roles
    int lane = t & 63;
    int wv   = t >> 6;           // 0..3 -> 64-node slab
    int lm   = lane & 7;         // node group (stride-1; nodes lm+8i)
    int ln   = lane >> 3;        // h group
    int n0   = ln * 8;

    float4 acc0[8], acc1[8];
#pragma unroll
    for (int i = 0; i < 8; ++i) {
        acc0[i] = make_float4(0.f, 0.f, 0.f, 0.f);
        acc1[i] = make_float4(0.f, 0.f, 0.f, 0.f);
    }

    float4 xreg[4];
    float4 wreg;

    // ---- tile load helpers (global -> regs) ----
    auto load_tile = [&](int kt) {
#pragma unroll
        for (int pass = 0; pass < 4; ++pass) {
            int g = nbase + pass * 64 + srow;
            g = g < N ? g : (N - 1);
            xreg[pass] = *reinterpret_cast<const float4*>(
                x + (size_t)g * DIM + kt * BK + schk * 4);
        }
        wreg = *reinterpret_cast<const float4*>(
            Ws1 + (size_t)(kt * BK + wrow) * HID + wchk * 4);
    };
    auto store_tile = [&](int b) {
#pragma unroll
        for (int pass = 0; pass < 4; ++pass) {
            int row = pass * 64 + srow;
            *reinterpret_cast<float4*>(&xs[b][row * XPAD + schk * 4]) = xreg[pass];
        }
        *reinterpret_cast<float4*>(&ws[b][wrow * WPAD + wchk * 4]) = wreg;
    };

    load_tile(0);
    store_tile(0);
    __syncthreads();

    for (int kt = 0; kt < DIM / BK; ++kt) {
        int b = kt & 1;
        if (kt + 1 < DIM / BK) load_tile(kt + 1);   // issue early: latency under compute

        const float* xb = xs[b];
        const float* wb = ws[b];
#pragma unroll
        for (int c = 0; c < 4; ++c) {               // 4 k-values per chunk
            float4 xf[8];
#pragma unroll
            for (int i = 0; i < 8; ++i)
                xf[i] = *reinterpret_cast<const float4*>(
                    &xb[(wv * 64 + lm + 8 * i) * XPAD + c * 4]);
#pragma unroll
            for (int kk = 0; kk < 4; ++kk) {
                float4 w0 = *reinterpret_cast<const float4*>(
                    &wb[(c * 4 + kk) * WPAD + n0]);
                float4 w1 = *reinterpret_cast<const float4*>(
                    &wb[(c * 4 + kk) * WPAD + n0 + 4]);
#pragma unroll
                for (int i = 0; i < 8; ++i) {
                    float xk = kk == 0 ? xf[i].x : kk == 1 ? xf[i].y
                             : kk == 2 ? xf[i].z : xf[i].w;
                    acc0[i].x = fmaf(xk, w0.x, acc0[i].x);
                    acc0[i].y = fmaf(xk, w0.y, acc0[i].y);
                    acc0[i].z = fmaf(xk, w0.z, acc0[i].z);
                    acc0[i].w = fmaf(xk, w0.w, acc0[i].w);
                    acc1[i].x = fmaf(xk, w1.x, acc1[i].x);
                    acc1[i].y = fmaf(xk, w1.y, acc1[i].y);
                    acc1[i].z = fmaf(xk, w1.z, acc1[i].z);
                    acc1[i].w = fmaf(xk, w1.w, acc1[i].w);
                }
            }
        }
        if (kt + 1 < DIM / BK) store_tile(b ^ 1);   // write next into other buffer
        __syncthreads();
    }

    // ---- epilogue: bias + ReLU + Ws2 dot, reduce over ln, store ----
    float4 b1a = *reinterpret_cast<const float4*>(bs1 + n0);
    float4 b1b = *reinterpret_cast<const float4*>(bs1 + n0 + 4);
    float4 w2a = *reinterpret_cast<const float4*>(Ws2 + n0);
    float4 w2b = *reinterpret_cast<const float4*>(Ws2 + n0 + 4);
    float p[8];
#pragma unroll
    for (int i = 0; i < 8; ++i) {
        float v = 0.0f;
        v = fmaf(fmaxf(acc0[i].x + b1a.x, 0.0f), w2a.x, v);
        v = fmaf(fmaxf(acc0[i].y + b1a.y, 0.0f), w2a.y, v);
        v = fmaf(fmaxf(acc0[i].z + b1a.z, 0.0f), w2a.z, v);
        v = fmaf(fmaxf(acc0[i].w + b1a.w, 0.0f), w2a.w, v);
        v = fmaf(fmaxf(acc1[i].x + b1b.x, 0.0f), w2b.x, v);
        v = fmaf(fmaxf(acc1[i].y + b1b.y, 0.0f), w2b.y, v);
        v = fmaf(fmaxf(acc1[i].z + b1b.z, 0.0f), w2b.z, v);
        v = fmaf(fmaxf(acc1[i].w + b1b.w, 0.0f), w2b.w, v);
        p[i] = v;
    }
#pragma unroll
    for (int m = 8; m <= 32; m <<= 1) {
#pragma unroll
        for (int i = 0; i < 8; ++i) p[i] += __shfl_xor(p[i], m, 64);
    }
    if (ln == 0) {
        float b2 = bs2[0];
#pragma unroll
        for (int i = 0; i < 8; ++i) {
            int node = nbase + wv * 64 + lm + 8 * i;
            if (node < N) score[node] = p[i] + b2;
        }
    }
}

// ------------------------------------------------------------- K2: edge count
__global__ __launch_bounds__(256) void k_edges(
    const int* __restrict__ esrc, const int* __restrict__ edst,
    int* __restrict__ counts, int E, int G)
{
    __shared__ int hist[256];
    for (int i = threadIdx.x; i < G; i += 256) hist[i] = 0;
    __syncthreads();

    int nchunk = E >> 2;
    const int4* s4 = reinterpret_cast<const int4*>(esrc);
    const int4* d4 = reinterpret_cast<const int4*>(edst);
    for (int c = blockIdx.x * 256 + threadIdx.x; c < nchunk; c += gridDim.x * 256) {
        int4 s = s4[c], d = d4[c];
        int g;
        g = s.x / NPG; if (g == d.x / NPG) atomicAdd(&hist[g], 1);
        g = s.y / NPG; if (g == d.y / NPG) atomicAdd(&hist[g], 1);
        g = s.z / NPG; if (g == d.z / NPG) atomicAdd(&hist[g], 1);
        g = s.w / NPG; if (g == d.w / NPG) atomicAdd(&hist[g], 1);
    }
    if (blockIdx.x == 0) {
        for (int e = (nchunk << 2) + threadIdx.x; e < E; e += 256) {
            int g = esrc[e] / NPG;
            if (g == edst[e] / NPG) atomicAdd(&hist[g], 1);
        }
    }
    __syncthreads();
    for (int i = threadIdx.x; i < G; i += 256)
        if (hist[i]) atomicAdd(&counts[i], hist[i]);
}

// ------------------------------------------- K3: per-graph avg + keep_num MLP
__global__ __launch_bounds__(256) void k_keep(
    const float* __restrict__ score,
    const int* __restrict__ counts,
    const float* __restrict__ Wp1,   // [3][HID]
    const float* __restrict__ bp1,   // [HID]
    const float* __restrict__ Wp2,   // [HID]
    const float* __restrict__ bp2,   // [1]
    int* __restrict__ keep_num)
{
    int g = blockIdx.x;
    __shared__ float red[256];
    const float* s = score + (size_t)g * NPG;
    float v = 0.0f;
    for (int i = threadIdx.x; i < NPG; i += 256) v += s[i];
    red[threadIdx.x] = v;
    __syncthreads();
    for (int off = 128; off >= 1; off >>= 1) {
        if (threadIdx.x < off) red[threadIdx.x] += red[threadIdx.x + off];
        __syncthreads();
    }
    if (threadIdx.x < 64) {
        float f0 = (float)NPG / RATIO_NORM;
        float f1 = red[0] / (float)NPG;
        float f2 = (float)counts[g] / (float)(NPG * (NPG - 1));
        int h = threadIdx.x;
        float hv = bp1[h];
        hv = fmaf(f0, Wp1[h], hv);
        hv = fmaf(f1, Wp1[HID + h], hv);
        hv = fmaf(f2, Wp1[2 * HID + h], hv);
        hv = fmaxf(hv, 0.0f) * Wp2[h];
#pragma unroll
        for (int m = 32; m >= 1; m >>= 1) hv += __shfl_xor(hv, m, 64);
        if (h == 0) {
            float z = hv + bp2[0];
            float kr = 1.0f / (1.0f + expf(-z));
            int kn = (int)((float)NPG * kr);
            keep_num[g] = kn < 2 ? 2 : kn;
        }
    }
}

// ---------------------------- K4a: per-graph rank -> mask (float) + gate tanh
__global__ __launch_bounds__(256) void k_rank(
    const float* __restrict__ score,
    const int* __restrict__ keep_num,
    float* __restrict__ out_mask,   // [N] 0.0/1.0
    float* __restrict__ gate)       // [N] tanh(score) or 0
{
    int g = blockIdx.x;
    __shared__ float s[NPG];
    const float* sg = score + (size_t)g * NPG;
    for (int i = threadIdx.x; i < NPG; i += 256) s[i] = sg[i];
    __syncthreads();

    int kn = keep_num[g];
    for (int i = threadIdx.x; i < NPG; i += 256) {
        float si = s[i];
        int rank = 0;
        for (int j = 0; j < NPG; ++j) {
            float sj = s[j];
            rank += (sj > si) || ((sj == si) && (j < i));
        }
        bool keep = rank < kn;
        size_t idx = (size_t)g * NPG + i;
        out_mask[idx] = keep ? 1.0f : 0.0f;
        gate[idx] = keep ? tanhf(si) : 0.0f;
    }
}

// ------------------------------------------ K4b: gated row write (full BW)
__global__ __launch_bounds__(256) void k_write(
    const float* __restrict__ x,
    const float* __restrict__ gate,
    float* __restrict__ out_x, int N)
{
    int lane = threadIdx.x & 63;
    int row = blockIdx.x * 4 + (threadIdx.x >> 6);
    if (row >= N) return;
    float gt = gate[row];
    size_t base = (size_t)row * DIM;
    float4* o = reinterpret_cast<float4*>(out_x + base);
    if (gt != 0.0f) {
        const float4* xi = reinterpret_cast<const float4*>(x + base);
        float4 v = xi[lane];
        o[lane] = make_float4(v.x * gt, v.y * gt, v.z * gt, v.w * gt);
    } else {
        o[lane] = make_float4(0.0f, 0.0f, 0.0f, 0.0f);
    }
}

// ---------------------------------------------------------------------- host
extern "C" void kernel_launch(void* const* d_in, const int* in_sizes, int n_in,
                              void* d_out, int out_size, void* d_ws, size_t ws_size,
                              hipStream_t stream)
{
    const float* x   = (const float*)d_in[0];
    const float* Ws1 = (const float*)d_in[1];
    const float* bs1 = (const float*)d_in[2];
    const float* Ws2 = (const float*)d_in[3];
    const float* bs2 = (const float*)d_in[4];
    const float* Wp1 = (const float*)d_in[5];
    const float* bp1 = (const float*)d_in[6];
    const float* Wp2 = (const float*)d_in[7];
    const float* bp2 = (const float*)d_in[8];
    const int* esrc  = (const int*)d_in[9];
    const int* edst  = (const int*)d_in[10];

    int E = in_sizes[9];
    int N = in_sizes[0] / DIM;
    int G = N / NPG;

    float* score = (float*)d_ws;                               // N floats
    float* gate  = score + N;                                  // N floats
    int* counts  = (int*)(gate + N);                           // G ints
    int* keep    = counts + G;                                 // G ints

    float* out_x    = (float*)d_out;
    float* out_mask = out_x + (size_t)N * DIM;

    hipMemsetAsync(counts, 0, G * sizeof(int), stream);
    k_score<<<(N + BM - 1) / BM, 256, 0, stream>>>(x, Ws1, bs1, Ws2, bs2, score, N);
    k_edges<<<512, 256, 0, stream>>>(esrc, edst, counts, E, G);
    k_keep<<<G, 256, 0, stream>>>(score, counts, Wp1, bp1, Wp2, bp2, keep);
    k_rank<<<G, 256, 0, stream>>>(score, keep, out_mask, gate);
    k_write<<<(N + 3) / 4, 256, 0, stream>>>(x, gate, out_x, N);
}